// Round 9
// baseline (561.243 us; speedup 1.0000x reference)
//
#include <hip/hip_runtime.h>
#include <hip/hip_cooperative_groups.h>

namespace cg = cooperative_groups;

#define D 64
#define LOG2E 1.4426950408889634f

#define BSH 7                     // bucket shift: 128-node buckets
#define BSZ 128                   // nodes per bucket

using frag_ab = __attribute__((ext_vector_type(8))) short;  // 8 bf16 (4 VGPRs)
using f32x4   = __attribute__((ext_vector_type(4))) float;  // 4 fp32 acc

__device__ __forceinline__ unsigned short f2bf(float f) {      // RNE fp32->bf16
    unsigned int bits = __float_as_uint(f);
    return (unsigned short)((bits + 0x7fffu + ((bits >> 16) & 1u)) >> 16);
}

__device__ __forceinline__ frag_ab pack8(float4 a, float4 b) { // 8 fp32 -> bf16x8 frag
    frag_ab f;
    f[0] = (short)f2bf(a.x); f[1] = (short)f2bf(a.y);
    f[2] = (short)f2bf(a.z); f[3] = (short)f2bf(a.w);
    f[4] = (short)f2bf(b.x); f[5] = (short)f2bf(b.y);
    f[6] = (short)f2bf(b.z); f[7] = (short)f2bf(b.w);
    return f;
}

// z = x @ W^T + b via MFMA bf16, LDS-free (R7: each wave's 16 rows are private).
// zxb[row*64+c] = { bf16(z_c) | bf16(x_c)<<16 }.
__global__ __launch_bounds__(256) void gemm_z(const float* __restrict__ x,
                                              const float* __restrict__ W,
                                              const float* __restrict__ b,
                                              unsigned int* __restrict__ zxb,
                                              int n) {
    int tid = threadIdx.x;
    int row0 = blockIdx.x * 64;
    int l  = tid & 63;    // lane
    int w  = tid >> 6;    // wave 0..3 -> rows w*16..w*16+15
    int lr = l & 15;      // A-row / B-col / D-col within 16-tile
    int hi = l >> 4;      // 0..3
    int lk = hi * 8;      // k offset within K=32 chunk

    int arow = row0 + w * 16 + lr;
    int crow = (arow < n) ? arow : (n - 1);       // clamp; stores are guarded
    const float* xp = x + (size_t)crow * 64;
    frag_ab afr[2];
#pragma unroll
    for (int ks = 0; ks < 2; ++ks) {
        const float* ap = xp + ks * 32 + lk;
        afr[ks] = pack8(*(const float4*)ap, *(const float4*)(ap + 4));
    }

    frag_ab bfr[4][2];
#pragma unroll
    for (int colt = 0; colt < 4; ++colt) {
#pragma unroll
        for (int ks = 0; ks < 2; ++ks) {
            const float* wp = W + (colt * 16 + lr) * 64 + ks * 32 + lk;
            bfr[colt][ks] = pack8(*(const float4*)wp, *(const float4*)(wp + 4));
        }
    }

    f32x4 zero = {0.f, 0.f, 0.f, 0.f};
    f32x4 acc[4] = {zero, zero, zero, zero};
#pragma unroll
    for (int ks = 0; ks < 2; ++ks) {
#pragma unroll
        for (int colt = 0; colt < 4; ++colt) {
            acc[colt] = __builtin_amdgcn_mfma_f32_16x16x32_bf16(
                afr[ks], bfr[colt][ks], acc[colt], 0, 0, 0);
        }
    }

    // D mapping: col=lane&15, row=(lane>>4)*4+reg (m89-verified)
#pragma unroll
    for (int colt = 0; colt < 4; ++colt) {
        int col = colt * 16 + lr;
        float bb = b[col];
#pragma unroll
        for (int r = 0; r < 4; ++r) {
            int row = row0 + w * 16 + hi * 4 + r;
            int rrow = (row < n) ? row : (n - 1);
            float z  = acc[colt][r] + bb;
            float xv = x[(size_t)rrow * 64 + col];
            unsigned int u = (unsigned int)f2bf(z) |
                             ((unsigned int)f2bf(xv) << 16);
            if (row < n)
                zxb[(size_t)row * 64 + col] = u;   // 64B-segment coalesced
        }
    }
}

// ONE cooperative kernel for the entire CSR build (was 6 dispatches):
//   ph1 hist (block b's 1535-edge chunk -> hist2d column b, bin-major)
//   ph2 per-bin row scan (block b scans bin-row b)
//   ph3 block 0 scans row totals -> rowBase (+ sentinel)
//   ph4 scatter (block b re-streams its chunk; bases = rowBase + scanned column)
//   ph5 bucket CSR (block b = bucket b: LDS count/scan -> rowstart + srcids)
// Grid = nb = 782 blocks x 256 thr; 5.5 KB LDS -> comfortably co-resident.
// Zero global atomics anywhere.
__global__ __launch_bounds__(256) void build_csr(const int* __restrict__ src,
                                                 const int* __restrict__ dst,
                                                 int* __restrict__ hist2d,
                                                 int* __restrict__ rowTot,
                                                 int* __restrict__ rowBase,
                                                 int* __restrict__ rowstart,
                                                 int* __restrict__ srcids,
                                                 unsigned int* __restrict__ packed,
                                                 int n, int e_cnt, int nb, int G,
                                                 int EPB) {
    cg::grid_group grid = cg::this_grid();
    __shared__ int cnt[1024];      // bins (nb <= 1024)
    __shared__ int red[256];
    __shared__ int cur[128];
    int t = threadIdx.x;
    int b = blockIdx.x;
    int elo = b * EPB;
    int ehi = elo + EPB; if (ehi > e_cnt) ehi = e_cnt;

    // ---- phase 1: histogram my chunk ----
    for (int i = t; i < nb; i += 256) cnt[i] = 0;
    __syncthreads();
    for (int e = elo + t; e < ehi; e += 256)
        atomicAdd(&cnt[dst[e] >> BSH], 1);          // LDS atomic
    __syncthreads();
    for (int i = t; i < nb; i += 256)
        hist2d[(size_t)i * G + b] = cnt[i];         // bin-major column store
    grid.sync();

    // ---- phase 2: exclusive scan of bin-row b (G entries), total -> rowTot[b] ----
    {
        int base = b * G;
        int j0 = 4 * t;
        int v0 = (j0 + 0 < G) ? hist2d[base + j0 + 0] : 0;
        int v1 = (j0 + 1 < G) ? hist2d[base + j0 + 1] : 0;
        int v2 = (j0 + 2 < G) ? hist2d[base + j0 + 2] : 0;
        int v3 = (j0 + 3 < G) ? hist2d[base + j0 + 3] : 0;
        int tsum = v0 + v1 + v2 + v3;
        red[t] = tsum;
        __syncthreads();
        for (int off = 1; off < 256; off <<= 1) {
            int u = (t >= off) ? red[t - off] : 0;
            __syncthreads();
            red[t] += u;
            __syncthreads();
        }
        int excl = red[t] - tsum;
        if (j0 + 0 < G) hist2d[base + j0 + 0] = excl;
        if (j0 + 1 < G) hist2d[base + j0 + 1] = excl + v0;
        if (j0 + 2 < G) hist2d[base + j0 + 2] = excl + v0 + v1;
        if (j0 + 3 < G) hist2d[base + j0 + 3] = excl + v0 + v1 + v2;
        if (t == 255) rowTot[b] = red[255];
    }
    grid.sync();

    // ---- phase 3: block 0 scans rowTot -> rowBase (exclusive), sentinel = e ----
    if (b == 0) {
        int j0 = 4 * t;
        int v0 = (j0 + 0 < nb) ? rowTot[j0 + 0] : 0;
        int v1 = (j0 + 1 < nb) ? rowTot[j0 + 1] : 0;
        int v2 = (j0 + 2 < nb) ? rowTot[j0 + 2] : 0;
        int v3 = (j0 + 3 < nb) ? rowTot[j0 + 3] : 0;
        int tsum = v0 + v1 + v2 + v3;
        red[t] = tsum;
        __syncthreads();
        for (int off = 1; off < 256; off <<= 1) {
            int u = (t >= off) ? red[t - off] : 0;
            __syncthreads();
            red[t] += u;
            __syncthreads();
        }
        int excl = red[t] - tsum;
        if (j0 + 0 < nb) rowBase[j0 + 0] = excl;
        if (j0 + 1 < nb) rowBase[j0 + 1] = excl + v0;
        if (j0 + 2 < nb) rowBase[j0 + 2] = excl + v0 + v1;
        if (j0 + 3 < nb) rowBase[j0 + 3] = excl + v0 + v1 + v2;
        if (t == 255) rowBase[nb] = red[255];       // == e_cnt
    }
    grid.sync();

    // ---- phase 4: scatter my chunk; base(bin,blk) = rowBase + scanned column ----
    for (int i = t; i < nb; i += 256)
        cnt[i] = rowBase[i] + hist2d[(size_t)i * G + b];
    __syncthreads();
    for (int e = elo + t; e < ehi; e += 256) {
        int d = dst[e];
        int pos = atomicAdd(&cnt[d >> BSH], 1);     // LDS atomic
        packed[pos] = (unsigned int)src[e] | ((unsigned int)(d & (BSZ - 1)) << 24);
    }
    grid.sync();

    // ---- phase 5: bucket CSR for bucket b ----
    {
        int lo = rowBase[b];
        int hi = rowBase[b + 1];
        int m = hi - lo;
        if (t < 128) cnt[t] = 0;
        __syncthreads();
        for (int i = t; i < m; i += 256)
            atomicAdd(&cnt[packed[lo + i] >> 24], 1);
        __syncthreads();
        int c = (t < 128) ? cnt[t] : 0;
        red[t] = c;
        __syncthreads();
        for (int off = 1; off < 128; off <<= 1) {
            int u = (t < 128 && t >= off) ? red[t - off] : 0;
            __syncthreads();
            if (t < 128) red[t] += u;
            __syncthreads();
        }
        if (t < 128) {
            int excl = red[t] - c;
            cur[t] = lo + excl;
            int node = (b << BSH) + t;
            if (node < n) rowstart[node] = lo + excl;
        }
        if (b == nb - 1 && t == 0) rowstart[n] = e_cnt;
        __syncthreads();
        for (int i = t; i < m; i += 256) {
            unsigned int p = packed[lo + i];
            int pos = atomicAdd(&cur[p >> 24], 1);   // LDS atomic
            srcids[pos] = (int)(p & 0xFFFFFFu);
        }
    }
}

// wave-per-node, quarter-wave per edge, 8 edges/iter (2x unroll); unmasked full
// iterations + one masked tail. lrelu = max(v, 0.2v) (2 ops, slope < 1).
// bf16-packed row: zxb[row*64 + d] = { bf16 z_d | bf16 x_d << 16 }, 256 B/row.
__global__ __launch_bounds__(256) void gather4b(const int* __restrict__ srcids,
                                                const int* __restrict__ rowstart,
                                                const unsigned int* __restrict__ zxb,
                                                const float* __restrict__ att,
                                                float* __restrict__ out, int n) {
    int lane = threadIdx.x & 63;
    int node = blockIdx.x * 4 + (threadIdx.x >> 6);
    if (node >= n) return;
    int q = lane & 15;                 // dim group: 4q..4q+3
    int h = lane >> 4;                 // edge slot 0..3
    int rs = rowstart[node], re = rowstart[node + 1];

    const uint4 zdv = *(const uint4*)(zxb + (size_t)node * 64 + 4 * q);
    float zd0 = __uint_as_float(zdv.x << 16);
    float zd1 = __uint_as_float(zdv.y << 16);
    float zd2 = __uint_as_float(zdv.z << 16);
    float zd3 = __uint_as_float(zdv.w << 16);
    float4 av = *(const float4*)(att + 4 * q);
    float a0 = av.x * LOG2E, a1 = av.y * LOG2E, a2 = av.z * LOG2E, a3 = av.w * LOG2E;

    float ax0 = 0.f, ax1 = 0.f, ax2 = 0.f, ax3 = 0.f, ssum = 0.f;
    int efull = rs + ((re - rs) & ~7);
    int e = rs;
    for (; e < efull; e += 8) {            // unmasked body
        int s0 = srcids[e + h];
        int s1 = srcids[e + 4 + h];
        const uint4 r0 = *(const uint4*)(zxb + (size_t)s0 * 64 + 4 * q);
        const uint4 r1 = *(const uint4*)(zxb + (size_t)s1 * 64 + 4 * q);

        float v0 = __uint_as_float(r0.x << 16) + zd0; v0 = fmaxf(v0, 0.2f * v0);
        float v1 = __uint_as_float(r0.y << 16) + zd1; v1 = fmaxf(v1, 0.2f * v1);
        float v2 = __uint_as_float(r0.z << 16) + zd2; v2 = fmaxf(v2, 0.2f * v2);
        float v3 = __uint_as_float(r0.w << 16) + zd3; v3 = fmaxf(v3, 0.2f * v3);
        float p0 = v0 * a0 + v1 * a1 + v2 * a2 + v3 * a3;

        float u0 = __uint_as_float(r1.x << 16) + zd0; u0 = fmaxf(u0, 0.2f * u0);
        float u1 = __uint_as_float(r1.y << 16) + zd1; u1 = fmaxf(u1, 0.2f * u1);
        float u2 = __uint_as_float(r1.z << 16) + zd2; u2 = fmaxf(u2, 0.2f * u2);
        float u3 = __uint_as_float(r1.w << 16) + zd3; u3 = fmaxf(u3, 0.2f * u3);
        float p1 = u0 * a0 + u1 * a1 + u2 * a2 + u3 * a3;

#pragma unroll
        for (int off = 8; off >= 1; off >>= 1) {
            p0 += __shfl_xor(p0, off, 64);
            p1 += __shfl_xor(p1, off, 64);
        }
        float ex0 = __builtin_exp2f(p0);
        float ex1 = __builtin_exp2f(p1);
        ssum += ex0 + ex1;
        ax0 += ex0 * __uint_as_float(r0.x & 0xffff0000u)
             + ex1 * __uint_as_float(r1.x & 0xffff0000u);
        ax1 += ex0 * __uint_as_float(r0.y & 0xffff0000u)
             + ex1 * __uint_as_float(r1.y & 0xffff0000u);
        ax2 += ex0 * __uint_as_float(r0.z & 0xffff0000u)
             + ex1 * __uint_as_float(r1.z & 0xffff0000u);
        ax3 += ex0 * __uint_as_float(r0.w & 0xffff0000u)
             + ex1 * __uint_as_float(r1.w & 0xffff0000u);
    }
    if (e < re) {                          // masked tail (1..7 edges)
        int e0i = e + h, e1i = e + 4 + h;
        bool l0 = e0i < re, l1 = e1i < re;
        int s0 = l0 ? srcids[e0i] : node;
        int s1 = l1 ? srcids[e1i] : node;
        const uint4 r0 = *(const uint4*)(zxb + (size_t)s0 * 64 + 4 * q);
        const uint4 r1 = *(const uint4*)(zxb + (size_t)s1 * 64 + 4 * q);

        float v0 = __uint_as_float(r0.x << 16) + zd0; v0 = fmaxf(v0, 0.2f * v0);
        float v1 = __uint_as_float(r0.y << 16) + zd1; v1 = fmaxf(v1, 0.2f * v1);
        float v2 = __uint_as_float(r0.z << 16) + zd2; v2 = fmaxf(v2, 0.2f * v2);
        float v3 = __uint_as_float(r0.w << 16) + zd3; v3 = fmaxf(v3, 0.2f * v3);
        float p0 = v0 * a0 + v1 * a1 + v2 * a2 + v3 * a3;

        float u0 = __uint_as_float(r1.x << 16) + zd0; u0 = fmaxf(u0, 0.2f * u0);
        float u1 = __uint_as_float(r1.y << 16) + zd1; u1 = fmaxf(u1, 0.2f * u1);
        float u2 = __uint_as_float(r1.z << 16) + zd2; u2 = fmaxf(u2, 0.2f * u2);
        float u3 = __uint_as_float(r1.w << 16) + zd3; u3 = fmaxf(u3, 0.2f * u3);
        float p1 = u0 * a0 + u1 * a1 + u2 * a2 + u3 * a3;

#pragma unroll
        for (int off = 8; off >= 1; off >>= 1) {
            p0 += __shfl_xor(p0, off, 64);
            p1 += __shfl_xor(p1, off, 64);
        }
        float ex0 = l0 ? __builtin_exp2f(p0) : 0.f;
        float ex1 = l1 ? __builtin_exp2f(p1) : 0.f;
        ssum += ex0 + ex1;
        ax0 += ex0 * __uint_as_float(r0.x & 0xffff0000u)
             + ex1 * __uint_as_float(r1.x & 0xffff0000u);
        ax1 += ex0 * __uint_as_float(r0.y & 0xffff0000u)
             + ex1 * __uint_as_float(r1.y & 0xffff0000u);
        ax2 += ex0 * __uint_as_float(r0.z & 0xffff0000u)
             + ex1 * __uint_as_float(r1.z & 0xffff0000u);
        ax3 += ex0 * __uint_as_float(r0.w & 0xffff0000u)
             + ex1 * __uint_as_float(r1.w & 0xffff0000u);
    }
    ssum += __shfl_xor(ssum, 16, 64); ssum += __shfl_xor(ssum, 32, 64);
    ax0  += __shfl_xor(ax0, 16, 64);  ax0  += __shfl_xor(ax0, 32, 64);
    ax1  += __shfl_xor(ax1, 16, 64);  ax1  += __shfl_xor(ax1, 32, 64);
    ax2  += __shfl_xor(ax2, 16, 64);  ax2  += __shfl_xor(ax2, 32, 64);
    ax3  += __shfl_xor(ax3, 16, 64);  ax3  += __shfl_xor(ax3, 32, 64);
    if (h == 0) {
        float inv = (re > rs) ? 1.f / ssum : 0.f;
        float4 o = make_float4(ax0 * inv, ax1 * inv, ax2 * inv, ax3 * inv);
        *(float4*)&out[(size_t)node * D + 4 * q] = o;
    }
}

extern "C" void kernel_launch(void* const* d_in, const int* in_sizes, int n_in,
                              void* d_out, int out_size, void* d_ws, size_t ws_size,
                              hipStream_t stream) {
    const float* x   = (const float*)d_in[0];
    const int*   ei  = (const int*)d_in[1];
    const float* W   = (const float*)d_in[2];
    const float* b   = (const float*)d_in[3];
    const float* att = (const float*)d_in[4];
    int n = in_sizes[0] / D;
    int e = in_sizes[1] / 2;
    const int* src = ei;
    const int* dst = ei + e;
    float* out = (float*)d_out;

    int gemmBlk = (n + 63) / 64;                 // 1563
    int nb      = (n + BSZ - 1) >> BSH;          // 782 buckets of 128
    int G       = nb;                            // cooperative grid = one block/bucket
    int EPB     = (e + G - 1) / G;               // 1535 edges per block chunk

    // ws: zxb[n*64 uint] | hist2d[nb*G] | rowTot[nb] | rowBase[nb+1]
    //     | rowstart[n+1] | srcids[e] | packed[e]
    unsigned int* zxb = (unsigned int*)d_ws;
    int* hist2d   = (int*)(zxb + (size_t)n * 64);
    int* rowTot   = hist2d + (size_t)nb * G;
    int* rowBase  = rowTot + nb;
    int* rowstart = rowBase + nb + 1;
    int* srcids   = rowstart + n + 1;
    unsigned int* packed = (unsigned int*)(srcids + e);

    gemm_z<<<gemmBlk, 256, 0, stream>>>(x, W, b, zxb, n);

    void* args[] = { (void*)&src, (void*)&dst, (void*)&hist2d, (void*)&rowTot,
                     (void*)&rowBase, (void*)&rowstart, (void*)&srcids,
                     (void*)&packed, (void*)&n, (void*)&e, (void*)&nb,
                     (void*)&G, (void*)&EPB };
    hipLaunchCooperativeKernel((const void*)build_csr, dim3(G), dim3(256),
                               args, 0, stream);

    gather4b<<<(n + 3) / 4, 256, 0, stream>>>(srcids, rowstart, zxb, att, out, n);
}

// Round 10
// 235.572 us; speedup vs baseline: 2.3825x; 2.3825x over previous
//
#include <hip/hip_runtime.h>

#define D 64
#define LOG2E 1.4426950408889634f

#define HEPT_H 32                 // edges/thread, fused hist blocks (8192/block)
#define SEPT 32                   // edges/thread, scatter (8192/block)
#define BSH 9                     // bucket shift: 512-node buckets
#define BSZ 512                   // nodes per bucket

using frag_ab = __attribute__((ext_vector_type(8))) short;  // 8 bf16 (4 VGPRs)
using f32x4   = __attribute__((ext_vector_type(4))) float;  // 4 fp32 acc

__device__ __forceinline__ unsigned short f2bf(float f) {      // RNE fp32->bf16
    unsigned int bits = __float_as_uint(f);
    return (unsigned short)((bits + 0x7fffu + ((bits >> 16) & 1u)) >> 16);
}

__device__ __forceinline__ frag_ab pack8(float4 a, float4 b) { // 8 fp32 -> bf16x8 frag
    frag_ab f;
    f[0] = (short)f2bf(a.x); f[1] = (short)f2bf(a.y);
    f[2] = (short)f2bf(a.z); f[3] = (short)f2bf(a.w);
    f[4] = (short)f2bf(b.x); f[5] = (short)f2bf(b.y);
    f[6] = (short)f2bf(b.z); f[7] = (short)f2bf(b.w);
    return f;
}

// Block-role fused kernel: blocks [0, histBlk) histogram dst>>BSH into a bin-major
// 2D count matrix hist2d[bin*nblk + blk] (plain stores, no global atomics);
// blocks [histBlk, ..) do z = x @ W^T + b via MFMA bf16, LDS-free (R7).
// zxb[row*64+c] = { bf16(z_c) | bf16(x_c)<<16 }.
__global__ __launch_bounds__(256) void gemm_z_hist(const float* __restrict__ x,
                                                   const float* __restrict__ W,
                                                   const float* __restrict__ b,
                                                   unsigned int* __restrict__ zxb,
                                                   int n,
                                                   const int* __restrict__ dst,
                                                   int* __restrict__ hist2d,
                                                   int e_cnt, int histBlk,
                                                   int nb, int nblk) {
    __shared__ int cnt[512];        // hist branch only (2 KB; nb <= 512)
    int tid = threadIdx.x;

    if ((int)blockIdx.x < histBlk) {
        for (int i = tid; i < nb; i += 256) cnt[i] = 0;
        __syncthreads();
        int base = blockIdx.x * (256 * HEPT_H);
        for (int j = 0; j < HEPT_H; ++j) {
            int e = base + j * 256 + tid;
            if (e < e_cnt) atomicAdd(&cnt[dst[e] >> BSH], 1);   // LDS atomic
        }
        __syncthreads();
        for (int i = tid; i < nb; i += 256)
            hist2d[(size_t)i * nblk + blockIdx.x] = cnt[i];     // bin-major store
        return;
    }

    int row0 = (blockIdx.x - histBlk) * 64;
    int l  = tid & 63;    // lane
    int w  = tid >> 6;    // wave 0..3 -> rows w*16..w*16+15
    int lr = l & 15;      // A-row / B-col / D-col within 16-tile
    int hi = l >> 4;      // 0..3
    int lk = hi * 8;      // k offset within K=32 chunk

    // A frags straight from global: wave reads 16 contiguous 256B rows (4 KB)
    int arow = row0 + w * 16 + lr;
    int crow = (arow < n) ? arow : (n - 1);       // clamp; stores are guarded
    const float* xp = x + (size_t)crow * 64;
    frag_ab afr[2];
#pragma unroll
    for (int ks = 0; ks < 2; ++ks) {
        const float* ap = xp + ks * 32 + lk;
        afr[ks] = pack8(*(const float4*)ap, *(const float4*)(ap + 4));
    }

    // B frags straight from W (16 KB, L1/L2-resident; B^T == W so k contiguous)
    frag_ab bfr[4][2];
#pragma unroll
    for (int colt = 0; colt < 4; ++colt) {
#pragma unroll
        for (int ks = 0; ks < 2; ++ks) {
            const float* wp = W + (colt * 16 + lr) * 64 + ks * 32 + lk;
            bfr[colt][ks] = pack8(*(const float4*)wp, *(const float4*)(wp + 4));
        }
    }

    f32x4 zero = {0.f, 0.f, 0.f, 0.f};
    f32x4 acc[4] = {zero, zero, zero, zero};
#pragma unroll
    for (int ks = 0; ks < 2; ++ks) {
#pragma unroll
        for (int colt = 0; colt < 4; ++colt) {
            acc[colt] = __builtin_amdgcn_mfma_f32_16x16x32_bf16(
                afr[ks], bfr[colt][ks], acc[colt], 0, 0, 0);
        }
    }

    // D mapping: col=lane&15, row=(lane>>4)*4+reg (m89-verified).
    // xv re-read from global is L1-hot (this block just streamed these rows).
#pragma unroll
    for (int colt = 0; colt < 4; ++colt) {
        int col = colt * 16 + lr;
        float bb = b[col];
#pragma unroll
        for (int r = 0; r < 4; ++r) {
            int row = row0 + w * 16 + hi * 4 + r;
            int rrow = (row < n) ? row : (n - 1);
            float z  = acc[colt][r] + bb;
            float xv = x[(size_t)rrow * 64 + col];
            unsigned int u = (unsigned int)f2bf(z) |
                             ((unsigned int)f2bf(xv) << 16);
            if (row < n)
                zxb[(size_t)row * 64 + col] = u;   // 64B-segment coalesced
        }
    }
}

// Single-dispatch exclusive scan of total_n (<= ~32K) ints, ONE block of 1024.
// Pass 1: per-thread chunk sum; block Hillis-Steele; pass 2: re-read (L2-hot)
// and write running prefix. In-place safe (each idx owned by one thread).
// Sentinel: data[total_n] = grand total. Replaces 3 scan dispatches.
__global__ __launch_bounds__(1024) void scan_all(int* data, int total_n, int C) {
    __shared__ int tot[1024];
    int t = threadIdx.x;
    int base = t * C;
    int s = 0;
    for (int j = 0; j < C; ++j) {
        int idx = base + j;
        if (idx < total_n) s += data[idx];
    }
    tot[t] = s;
    __syncthreads();
    for (int off = 1; off < 1024; off <<= 1) {
        int u = (t >= off) ? tot[t - off] : 0;
        __syncthreads();
        tot[t] += u;
        __syncthreads();
    }
    int run = tot[t] - s;       // exclusive prefix of this chunk
    for (int j = 0; j < C; ++j) {
        int idx = base + j;
        if (idx < total_n) {
            int v = data[idx];
            data[idx] = run;
            run += v;
        }
    }
    if (t == 1023) data[total_n] = tot[1023];
}

// Partition edges into 512-node buckets: packed[pos] = src | (dst&511)<<17
// (src < 2^17). Per-block bases straight from the scanned 2D histogram ->
// disjoint ranges, zero global atomics. Runs avg 8192/196 = 42 ints (~2.6
// lines) -> good write combining (R8 lesson: short runs killed it).
__global__ __launch_bounds__(256) void msd_scatter(const int* __restrict__ src,
                                                   const int* __restrict__ dst,
                                                   const int* __restrict__ histS,
                                                   unsigned int* __restrict__ packed,
                                                   int e_cnt, int nb, int nblk) {
    __shared__ int cnt[512];
    int t = threadIdx.x;
    int blk = blockIdx.x;
    for (int i = t; i < nb; i += 256) cnt[i] = histS[(size_t)i * nblk + blk];
    __syncthreads();
    int base = blk * (256 * SEPT);
    for (int j = 0; j < SEPT; ++j) {
        int e = base + j * 256 + t;
        if (e < e_cnt) {
            int d = dst[e];
            int pos = atomicAdd(&cnt[d >> BSH], 1);          // LDS atomic only
            packed[pos] = (unsigned int)src[e] |
                          ((unsigned int)(d & (BSZ - 1)) << 17);
        }
    }
}

// One block (512 thr) per 512-node bucket (~6122 edges avg, 196 blocks).
// LDS count + scan -> rowstart written directly; srcids scattered within the
// bucket's contiguous ~24 KB (L2-hot) region.
__global__ __launch_bounds__(512) void bucket_csr(const unsigned int* __restrict__ packed,
                                                  const int* __restrict__ histS,
                                                  int* __restrict__ rowstart,
                                                  int* __restrict__ srcids,
                                                  int n, int e_cnt, int nb, int nblk) {
    __shared__ int cnt[512];
    __shared__ int red[512];
    __shared__ int cur[512];
    int t = threadIdx.x;
    int b = blockIdx.x;
    int lo = histS[(size_t)b * nblk];
    int hi = histS[(size_t)(b + 1) * nblk];   // b==nb-1 hits sentinel == e_cnt
    int m = hi - lo;

    cnt[t] = 0;
    __syncthreads();
    for (int i = t; i < m; i += 512)
        atomicAdd(&cnt[packed[lo + i] >> 17], 1);
    __syncthreads();
    int c = cnt[t];
    red[t] = c;
    __syncthreads();
    for (int off = 1; off < 512; off <<= 1) {
        int u = (t >= off) ? red[t - off] : 0;
        __syncthreads();
        red[t] += u;
        __syncthreads();
    }
    int excl = red[t] - c;
    cur[t] = lo + excl;
    int node = (b << BSH) + t;
    if (node < n) rowstart[node] = lo + excl;
    if (b == nb - 1 && t == 0) rowstart[n] = e_cnt;
    __syncthreads();
    for (int i = t; i < m; i += 512) {
        unsigned int p = packed[lo + i];
        int pos = atomicAdd(&cur[p >> 17], 1);     // LDS atomic
        srcids[pos] = (int)(p & 0x1FFFFu);
    }
}

// wave-per-node, quarter-wave per edge, 8 edges/iter (2x unroll); unmasked full
// iterations + one masked tail. lrelu = max(v, 0.2v) (2 ops, slope < 1).
// bf16-packed row: zxb[row*64 + d] = { bf16 z_d | bf16 x_d << 16 }, 256 B/row.
__global__ __launch_bounds__(256) void gather4b(const int* __restrict__ srcids,
                                                const int* __restrict__ rowstart,
                                                const unsigned int* __restrict__ zxb,
                                                const float* __restrict__ att,
                                                float* __restrict__ out, int n) {
    int lane = threadIdx.x & 63;
    int node = blockIdx.x * 4 + (threadIdx.x >> 6);
    if (node >= n) return;
    int q = lane & 15;                 // dim group: 4q..4q+3
    int h = lane >> 4;                 // edge slot 0..3
    int rs = rowstart[node], re = rowstart[node + 1];

    const uint4 zdv = *(const uint4*)(zxb + (size_t)node * 64 + 4 * q);
    float zd0 = __uint_as_float(zdv.x << 16);
    float zd1 = __uint_as_float(zdv.y << 16);
    float zd2 = __uint_as_float(zdv.z << 16);
    float zd3 = __uint_as_float(zdv.w << 16);
    float4 av = *(const float4*)(att + 4 * q);
    float a0 = av.x * LOG2E, a1 = av.y * LOG2E, a2 = av.z * LOG2E, a3 = av.w * LOG2E;

    float ax0 = 0.f, ax1 = 0.f, ax2 = 0.f, ax3 = 0.f, ssum = 0.f;
    int efull = rs + ((re - rs) & ~7);
    int e = rs;
    for (; e < efull; e += 8) {            // unmasked body
        int s0 = srcids[e + h];
        int s1 = srcids[e + 4 + h];
        const uint4 r0 = *(const uint4*)(zxb + (size_t)s0 * 64 + 4 * q);
        const uint4 r1 = *(const uint4*)(zxb + (size_t)s1 * 64 + 4 * q);

        float v0 = __uint_as_float(r0.x << 16) + zd0; v0 = fmaxf(v0, 0.2f * v0);
        float v1 = __uint_as_float(r0.y << 16) + zd1; v1 = fmaxf(v1, 0.2f * v1);
        float v2 = __uint_as_float(r0.z << 16) + zd2; v2 = fmaxf(v2, 0.2f * v2);
        float v3 = __uint_as_float(r0.w << 16) + zd3; v3 = fmaxf(v3, 0.2f * v3);
        float p0 = v0 * a0 + v1 * a1 + v2 * a2 + v3 * a3;

        float u0 = __uint_as_float(r1.x << 16) + zd0; u0 = fmaxf(u0, 0.2f * u0);
        float u1 = __uint_as_float(r1.y << 16) + zd1; u1 = fmaxf(u1, 0.2f * u1);
        float u2 = __uint_as_float(r1.z << 16) + zd2; u2 = fmaxf(u2, 0.2f * u2);
        float u3 = __uint_as_float(r1.w << 16) + zd3; u3 = fmaxf(u3, 0.2f * u3);
        float p1 = u0 * a0 + u1 * a1 + u2 * a2 + u3 * a3;

#pragma unroll
        for (int off = 8; off >= 1; off >>= 1) {
            p0 += __shfl_xor(p0, off, 64);
            p1 += __shfl_xor(p1, off, 64);
        }
        float ex0 = __builtin_exp2f(p0);
        float ex1 = __builtin_exp2f(p1);
        ssum += ex0 + ex1;
        ax0 += ex0 * __uint_as_float(r0.x & 0xffff0000u)
             + ex1 * __uint_as_float(r1.x & 0xffff0000u);
        ax1 += ex0 * __uint_as_float(r0.y & 0xffff0000u)
             + ex1 * __uint_as_float(r1.y & 0xffff0000u);
        ax2 += ex0 * __uint_as_float(r0.z & 0xffff0000u)
             + ex1 * __uint_as_float(r1.z & 0xffff0000u);
        ax3 += ex0 * __uint_as_float(r0.w & 0xffff0000u)
             + ex1 * __uint_as_float(r1.w & 0xffff0000u);
    }
    if (e < re) {                          // masked tail (1..7 edges)
        int e0i = e + h, e1i = e + 4 + h;
        bool l0 = e0i < re, l1 = e1i < re;
        int s0 = l0 ? srcids[e0i] : node;
        int s1 = l1 ? srcids[e1i] : node;
        const uint4 r0 = *(const uint4*)(zxb + (size_t)s0 * 64 + 4 * q);
        const uint4 r1 = *(const uint4*)(zxb + (size_t)s1 * 64 + 4 * q);

        float v0 = __uint_as_float(r0.x << 16) + zd0; v0 = fmaxf(v0, 0.2f * v0);
        float v1 = __uint_as_float(r0.y << 16) + zd1; v1 = fmaxf(v1, 0.2f * v1);
        float v2 = __uint_as_float(r0.z << 16) + zd2; v2 = fmaxf(v2, 0.2f * v2);
        float v3 = __uint_as_float(r0.w << 16) + zd3; v3 = fmaxf(v3, 0.2f * v3);
        float p0 = v0 * a0 + v1 * a1 + v2 * a2 + v3 * a3;

        float u0 = __uint_as_float(r1.x << 16) + zd0; u0 = fmaxf(u0, 0.2f * u0);
        float u1 = __uint_as_float(r1.y << 16) + zd1; u1 = fmaxf(u1, 0.2f * u1);
        float u2 = __uint_as_float(r1.z << 16) + zd2; u2 = fmaxf(u2, 0.2f * u2);
        float u3 = __uint_as_float(r1.w << 16) + zd3; u3 = fmaxf(u3, 0.2f * u3);
        float p1 = u0 * a0 + u1 * a1 + u2 * a2 + u3 * a3;

#pragma unroll
        for (int off = 8; off >= 1; off >>= 1) {
            p0 += __shfl_xor(p0, off, 64);
            p1 += __shfl_xor(p1, off, 64);
        }
        float ex0 = l0 ? __builtin_exp2f(p0) : 0.f;
        float ex1 = l1 ? __builtin_exp2f(p1) : 0.f;
        ssum += ex0 + ex1;
        ax0 += ex0 * __uint_as_float(r0.x & 0xffff0000u)
             + ex1 * __uint_as_float(r1.x & 0xffff0000u);
        ax1 += ex0 * __uint_as_float(r0.y & 0xffff0000u)
             + ex1 * __uint_as_float(r1.y & 0xffff0000u);
        ax2 += ex0 * __uint_as_float(r0.z & 0xffff0000u)
             + ex1 * __uint_as_float(r1.z & 0xffff0000u);
        ax3 += ex0 * __uint_as_float(r0.w & 0xffff0000u)
             + ex1 * __uint_as_float(r1.w & 0xffff0000u);
    }
    ssum += __shfl_xor(ssum, 16, 64); ssum += __shfl_xor(ssum, 32, 64);
    ax0  += __shfl_xor(ax0, 16, 64);  ax0  += __shfl_xor(ax0, 32, 64);
    ax1  += __shfl_xor(ax1, 16, 64);  ax1  += __shfl_xor(ax1, 32, 64);
    ax2  += __shfl_xor(ax2, 16, 64);  ax2  += __shfl_xor(ax2, 32, 64);
    ax3  += __shfl_xor(ax3, 16, 64);  ax3  += __shfl_xor(ax3, 32, 64);
    if (h == 0) {
        float inv = (re > rs) ? 1.f / ssum : 0.f;
        float4 o = make_float4(ax0 * inv, ax1 * inv, ax2 * inv, ax3 * inv);
        *(float4*)&out[(size_t)node * D + 4 * q] = o;
    }
}

extern "C" void kernel_launch(void* const* d_in, const int* in_sizes, int n_in,
                              void* d_out, int out_size, void* d_ws, size_t ws_size,
                              hipStream_t stream) {
    const float* x   = (const float*)d_in[0];
    const int*   ei  = (const int*)d_in[1];
    const float* W   = (const float*)d_in[2];
    const float* b   = (const float*)d_in[3];
    const float* att = (const float*)d_in[4];
    int n = in_sizes[0] / D;
    int e = in_sizes[1] / 2;
    const int* src = ei;
    const int* dst = ei + e;
    float* out = (float*)d_out;

    int gemmBlk = (n + 63) / 64;                             // 1563
    int nb      = (n + BSZ - 1) >> BSH;                      // 196 buckets of 512
    int histBlk = (e + 256 * HEPT_H - 1) / (256 * HEPT_H);   // 147
    int nblk    = histBlk;
    int scatBlk = (e + 256 * SEPT - 1) / (256 * SEPT);       // 147
    int NBH     = nb * nblk;                                 // 28,812 cells
    int chunk   = (NBH + 1023) / 1024;                       // 29 per scan thread

    // ws: zxb[n*64 uint] | hist2d[NBH+1] | rowstart[n+1] | srcids[e] | packed[e]
    unsigned int* zxb = (unsigned int*)d_ws;
    int* hist2d   = (int*)(zxb + (size_t)n * 64);
    int* rowstart = hist2d + NBH + 1;
    int* srcids   = rowstart + n + 1;
    unsigned int* packed = (unsigned int*)(srcids + e);

    gemm_z_hist<<<histBlk + gemmBlk, 256, 0, stream>>>(x, W, b, zxb, n,
                                                       dst, hist2d, e, histBlk, nb, nblk);
    scan_all<<<1, 1024, 0, stream>>>(hist2d, NBH, chunk);
    msd_scatter<<<scatBlk, 256, 0, stream>>>(src, dst, hist2d, packed, e, nb, nblk);
    bucket_csr<<<nb, 512, 0, stream>>>(packed, hist2d, rowstart, srcids, n, e, nb, nblk);
    gather4b<<<(n + 3) / 4, 256, 0, stream>>>(srcids, rowstart, zxb, att, out, n);
}

// Round 11
// 198.269 us; speedup vs baseline: 2.8307x; 1.1881x over previous
//
#include <hip/hip_runtime.h>

#define D 64
#define LOG2E 1.4426950408889634f

#define HEPT_H 32                 // edges/thread, fused hist blocks (8192/block)
#define SEPT 32                   // edges/thread, scatter (8192/block)
#define BSH 7                     // bucket shift: 128-node buckets
#define BSZ 128                   // nodes per bucket

using frag_ab = __attribute__((ext_vector_type(8))) short;  // 8 bf16 (4 VGPRs)
using f32x4   = __attribute__((ext_vector_type(4))) float;  // 4 fp32 acc

__device__ __forceinline__ unsigned short f2bf(float f) {      // RNE fp32->bf16
    unsigned int bits = __float_as_uint(f);
    return (unsigned short)((bits + 0x7fffu + ((bits >> 16) & 1u)) >> 16);
}

__device__ __forceinline__ frag_ab pack8(float4 a, float4 b) { // 8 fp32 -> bf16x8 frag
    frag_ab f;
    f[0] = (short)f2bf(a.x); f[1] = (short)f2bf(a.y);
    f[2] = (short)f2bf(a.z); f[3] = (short)f2bf(a.w);
    f[4] = (short)f2bf(b.x); f[5] = (short)f2bf(b.y);
    f[6] = (short)f2bf(b.z); f[7] = (short)f2bf(b.w);
    return f;
}

// Block-role fused kernel: blocks [0, histBlk) histogram dst>>BSH into a bin-major
// 2D count matrix hist2d[bin*nblk + blk] (plain stores, no global atomics);
// blocks [histBlk, ..) do z = x @ W^T + b via MFMA bf16, LDS-free (R7).
// zxb[row*64+c] = { bf16(z_c) | bf16(x_c)<<16 }.
__global__ __launch_bounds__(256) void gemm_z_hist(const float* __restrict__ x,
                                                   const float* __restrict__ W,
                                                   const float* __restrict__ b,
                                                   unsigned int* __restrict__ zxb,
                                                   int n,
                                                   const int* __restrict__ dst,
                                                   int* __restrict__ hist2d,
                                                   int e_cnt, int histBlk,
                                                   int nb, int nblk) {
    __shared__ int cnt[2048];       // hist branch only (8 KB; nb <= 2048)
    int tid = threadIdx.x;

    if ((int)blockIdx.x < histBlk) {
        for (int i = tid; i < nb; i += 256) cnt[i] = 0;
        __syncthreads();
        int base = blockIdx.x * (256 * HEPT_H);
        for (int j = 0; j < HEPT_H; ++j) {
            int e = base + j * 256 + tid;
            if (e < e_cnt) atomicAdd(&cnt[dst[e] >> BSH], 1);   // LDS atomic
        }
        __syncthreads();
        for (int i = tid; i < nb; i += 256)
            hist2d[(size_t)i * nblk + blockIdx.x] = cnt[i];     // bin-major store
        return;
    }

    int row0 = (blockIdx.x - histBlk) * 64;
    int l  = tid & 63;    // lane
    int w  = tid >> 6;    // wave 0..3 -> rows w*16..w*16+15
    int lr = l & 15;      // A-row / B-col / D-col within 16-tile
    int hi = l >> 4;      // 0..3
    int lk = hi * 8;      // k offset within K=32 chunk

    // A frags straight from global: wave reads 16 contiguous 256B rows (4 KB)
    int arow = row0 + w * 16 + lr;
    int crow = (arow < n) ? arow : (n - 1);       // clamp; stores are guarded
    const float* xp = x + (size_t)crow * 64;
    frag_ab afr[2];
#pragma unroll
    for (int ks = 0; ks < 2; ++ks) {
        const float* ap = xp + ks * 32 + lk;
        afr[ks] = pack8(*(const float4*)ap, *(const float4*)(ap + 4));
    }

    // B frags straight from W (16 KB, L1/L2-resident; B^T == W so k contiguous)
    frag_ab bfr[4][2];
#pragma unroll
    for (int colt = 0; colt < 4; ++colt) {
#pragma unroll
        for (int ks = 0; ks < 2; ++ks) {
            const float* wp = W + (colt * 16 + lr) * 64 + ks * 32 + lk;
            bfr[colt][ks] = pack8(*(const float4*)wp, *(const float4*)(wp + 4));
        }
    }

    f32x4 zero = {0.f, 0.f, 0.f, 0.f};
    f32x4 acc[4] = {zero, zero, zero, zero};
#pragma unroll
    for (int ks = 0; ks < 2; ++ks) {
#pragma unroll
        for (int colt = 0; colt < 4; ++colt) {
            acc[colt] = __builtin_amdgcn_mfma_f32_16x16x32_bf16(
                afr[ks], bfr[colt][ks], acc[colt], 0, 0, 0);
        }
    }

    // D mapping: col=lane&15, row=(lane>>4)*4+reg (m89-verified).
    // xv re-read from global is L1-hot (this block just streamed these rows).
#pragma unroll
    for (int colt = 0; colt < 4; ++colt) {
        int col = colt * 16 + lr;
        float bb = b[col];
#pragma unroll
        for (int r = 0; r < 4; ++r) {
            int row = row0 + w * 16 + hi * 4 + r;
            int rrow = (row < n) ? row : (n - 1);
            float z  = acc[colt][r] + bb;
            float xv = x[(size_t)rrow * 64 + col];
            unsigned int u = (unsigned int)f2bf(z) |
                             ((unsigned int)f2bf(xv) << 16);
            if (row < n)
                zxb[(size_t)row * 64 + col] = u;   // 64B-segment coalesced
        }
    }
}

// ---- 3-phase coalesced scan over the bin-major histogram (atomic-free) ----
__global__ __launch_bounds__(256) void scan_part(const int* __restrict__ data,
                                                 int* __restrict__ part, int n) {
    __shared__ int red[256];
    int t = threadIdx.x;
    int i = blockIdx.x * 256 + t;
    red[t] = (i < n) ? data[i] : 0;
    __syncthreads();
    for (int off = 128; off >= 1; off >>= 1) {
        if (t < off) red[t] += red[t + off];
        __syncthreads();
    }
    if (t == 0) part[blockIdx.x] = red[0];
}

__global__ __launch_bounds__(1024) void scan_top(int* __restrict__ part, int B) {
    __shared__ int s[1024];
    int t = threadIdx.x;
    int v = (t < B) ? part[t] : 0;
    s[t] = v;
    __syncthreads();
    for (int off = 1; off < 1024; off <<= 1) {
        int u = (t >= off) ? s[t - off] : 0;
        __syncthreads();
        s[t] += u;
        __syncthreads();
    }
    if (t < B) part[t] = s[t] - v;   // exclusive
}

// in-place exclusive scan finalize (read-before-write, 1 thread per index).
// Writes total at data[n] as sentinel.
__global__ __launch_bounds__(256) void scan_final_ip(int* data,
                                                     const int* __restrict__ part, int n) {
    __shared__ int s[256];
    int t = threadIdx.x;
    int i = blockIdx.x * 256 + t;
    int v = (i < n) ? data[i] : 0;
    s[t] = v;
    __syncthreads();
    for (int off = 1; off < 256; off <<= 1) {
        int u = (t >= off) ? s[t - off] : 0;
        __syncthreads();
        s[t] += u;
        __syncthreads();
    }
    int incl = s[t] + part[blockIdx.x];
    if (i < n) data[i] = incl - v;
    if (i == n - 1) data[n] = incl;
}

// Partition edges into 128-node buckets: packed[pos] = src | (dst&127)<<24.
// Per-block bases come straight from the scanned 2D histogram -> disjoint output
// ranges with ZERO global atomics.
__global__ __launch_bounds__(256) void msd_scatter(const int* __restrict__ src,
                                                   const int* __restrict__ dst,
                                                   const int* __restrict__ histS,
                                                   unsigned int* __restrict__ packed,
                                                   int e_cnt, int nb, int nblk) {
    __shared__ int cnt[1024];
    int t = threadIdx.x;
    int blk = blockIdx.x;
    for (int i = t; i < nb; i += 256) cnt[i] = histS[(size_t)i * nblk + blk];
    __syncthreads();
    int base = blk * (256 * SEPT);
    for (int j = 0; j < SEPT; ++j) {
        int e = base + j * 256 + t;
        if (e < e_cnt) {
            int d = dst[e];
            int pos = atomicAdd(&cnt[d >> BSH], 1);          // LDS atomic only
            packed[pos] = (unsigned int)src[e] | ((unsigned int)(d & (BSZ - 1)) << 24);
        }
    }
}

// One block per 128-node bucket (~1536 edges avg, 782 blocks). LDS count + scan ->
// rowstart written directly; srcids scattered within the bucket's contiguous region.
__global__ __launch_bounds__(256) void bucket_csr(const unsigned int* __restrict__ packed,
                                                  const int* __restrict__ histS,
                                                  int* __restrict__ rowstart,
                                                  int* __restrict__ srcids,
                                                  int n, int e_cnt, int nb, int nblk) {
    __shared__ int cnt[128];
    __shared__ int sc[128];
    __shared__ int cur[128];
    int t = threadIdx.x;
    int b = blockIdx.x;
    int lo = histS[(size_t)b * nblk];
    int hi = histS[(size_t)(b + 1) * nblk];   // b==nb-1 hits sentinel == e_cnt
    int m = hi - lo;

    if (t < 128) cnt[t] = 0;
    __syncthreads();
    for (int i = t; i < m; i += 256)
        atomicAdd(&cnt[packed[lo + i] >> 24], 1);
    __syncthreads();
    if (t < 128) sc[t] = cnt[t];
    __syncthreads();
    for (int off = 1; off < 128; off <<= 1) {
        int u = (t < 128 && t >= off) ? sc[t - off] : 0;
        __syncthreads();
        if (t < 128) sc[t] += u;
        __syncthreads();
    }
    if (t < 128) {
        int excl = sc[t] - cnt[t];
        cur[t] = lo + excl;
        int node = (b << BSH) + t;
        if (node < n) rowstart[node] = lo + excl;
    }
    if (b == nb - 1 && t == 0) rowstart[n] = e_cnt;
    __syncthreads();
    for (int i = t; i < m; i += 256) {
        unsigned int p = packed[lo + i];
        int pos = atomicAdd(&cur[p >> 24], 1);     // LDS atomic
        srcids[pos] = (int)(p & 0xFFFFFFu);
    }
}

// wave-per-node, quarter-wave per edge. Full 8-edge bodies (best amortization),
// then a full 4-edge body if >=4 remain, then one masked 4-edge body (1-3 edges).
// Tail-waste: avg 5 slot-units/node vs 7 with the old 8-wide masked tail.
// lrelu = max(v, 0.2v). zxb[row*64+d] = { bf16 z_d | bf16 x_d << 16 }, 256 B/row.
__global__ __launch_bounds__(256) void gather4b(const int* __restrict__ srcids,
                                                const int* __restrict__ rowstart,
                                                const unsigned int* __restrict__ zxb,
                                                const float* __restrict__ att,
                                                float* __restrict__ out, int n) {
    int lane = threadIdx.x & 63;
    int node = blockIdx.x * 4 + (threadIdx.x >> 6);
    if (node >= n) return;
    int q = lane & 15;                 // dim group: 4q..4q+3
    int h = lane >> 4;                 // edge slot 0..3
    int rs = rowstart[node], re = rowstart[node + 1];

    const uint4 zdv = *(const uint4*)(zxb + (size_t)node * 64 + 4 * q);
    float zd0 = __uint_as_float(zdv.x << 16);
    float zd1 = __uint_as_float(zdv.y << 16);
    float zd2 = __uint_as_float(zdv.z << 16);
    float zd3 = __uint_as_float(zdv.w << 16);
    float4 av = *(const float4*)(att + 4 * q);
    float a0 = av.x * LOG2E, a1 = av.y * LOG2E, a2 = av.z * LOG2E, a3 = av.w * LOG2E;

    float ax0 = 0.f, ax1 = 0.f, ax2 = 0.f, ax3 = 0.f, ssum = 0.f;
    int e = rs;
    for (; e + 8 <= re; e += 8) {          // full 8-edge bodies
        int s0 = srcids[e + h];
        int s1 = srcids[e + 4 + h];
        const uint4 r0 = *(const uint4*)(zxb + (size_t)s0 * 64 + 4 * q);
        const uint4 r1 = *(const uint4*)(zxb + (size_t)s1 * 64 + 4 * q);

        float v0 = __uint_as_float(r0.x << 16) + zd0; v0 = fmaxf(v0, 0.2f * v0);
        float v1 = __uint_as_float(r0.y << 16) + zd1; v1 = fmaxf(v1, 0.2f * v1);
        float v2 = __uint_as_float(r0.z << 16) + zd2; v2 = fmaxf(v2, 0.2f * v2);
        float v3 = __uint_as_float(r0.w << 16) + zd3; v3 = fmaxf(v3, 0.2f * v3);
        float p0 = v0 * a0 + v1 * a1 + v2 * a2 + v3 * a3;

        float u0 = __uint_as_float(r1.x << 16) + zd0; u0 = fmaxf(u0, 0.2f * u0);
        float u1 = __uint_as_float(r1.y << 16) + zd1; u1 = fmaxf(u1, 0.2f * u1);
        float u2 = __uint_as_float(r1.z << 16) + zd2; u2 = fmaxf(u2, 0.2f * u2);
        float u3 = __uint_as_float(r1.w << 16) + zd3; u3 = fmaxf(u3, 0.2f * u3);
        float p1 = u0 * a0 + u1 * a1 + u2 * a2 + u3 * a3;

#pragma unroll
        for (int off = 8; off >= 1; off >>= 1) {
            p0 += __shfl_xor(p0, off, 64);
            p1 += __shfl_xor(p1, off, 64);
        }
        float ex0 = __builtin_exp2f(p0);
        float ex1 = __builtin_exp2f(p1);
        ssum += ex0 + ex1;
        ax0 += ex0 * __uint_as_float(r0.x & 0xffff0000u)
             + ex1 * __uint_as_float(r1.x & 0xffff0000u);
        ax1 += ex0 * __uint_as_float(r0.y & 0xffff0000u)
             + ex1 * __uint_as_float(r1.y & 0xffff0000u);
        ax2 += ex0 * __uint_as_float(r0.z & 0xffff0000u)
             + ex1 * __uint_as_float(r1.z & 0xffff0000u);
        ax3 += ex0 * __uint_as_float(r0.w & 0xffff0000u)
             + ex1 * __uint_as_float(r1.w & 0xffff0000u);
    }
    if (e + 4 <= re) {                     // full 4-edge body (no masks)
        int s0 = srcids[e + h];
        const uint4 r0 = *(const uint4*)(zxb + (size_t)s0 * 64 + 4 * q);
        float v0 = __uint_as_float(r0.x << 16) + zd0; v0 = fmaxf(v0, 0.2f * v0);
        float v1 = __uint_as_float(r0.y << 16) + zd1; v1 = fmaxf(v1, 0.2f * v1);
        float v2 = __uint_as_float(r0.z << 16) + zd2; v2 = fmaxf(v2, 0.2f * v2);
        float v3 = __uint_as_float(r0.w << 16) + zd3; v3 = fmaxf(v3, 0.2f * v3);
        float p0 = v0 * a0 + v1 * a1 + v2 * a2 + v3 * a3;
#pragma unroll
        for (int off = 8; off >= 1; off >>= 1) p0 += __shfl_xor(p0, off, 64);
        float ex0 = __builtin_exp2f(p0);
        ssum += ex0;
        ax0 += ex0 * __uint_as_float(r0.x & 0xffff0000u);
        ax1 += ex0 * __uint_as_float(r0.y & 0xffff0000u);
        ax2 += ex0 * __uint_as_float(r0.z & 0xffff0000u);
        ax3 += ex0 * __uint_as_float(r0.w & 0xffff0000u);
        e += 4;
    }
    if (e < re) {                          // masked 4-edge body (1..3 edges)
        int e0i = e + h;
        bool l0 = e0i < re;
        int s0 = l0 ? srcids[e0i] : node;
        const uint4 r0 = *(const uint4*)(zxb + (size_t)s0 * 64 + 4 * q);
        float v0 = __uint_as_float(r0.x << 16) + zd0; v0 = fmaxf(v0, 0.2f * v0);
        float v1 = __uint_as_float(r0.y << 16) + zd1; v1 = fmaxf(v1, 0.2f * v1);
        float v2 = __uint_as_float(r0.z << 16) + zd2; v2 = fmaxf(v2, 0.2f * v2);
        float v3 = __uint_as_float(r0.w << 16) + zd3; v3 = fmaxf(v3, 0.2f * v3);
        float p0 = v0 * a0 + v1 * a1 + v2 * a2 + v3 * a3;
#pragma unroll
        for (int off = 8; off >= 1; off >>= 1) p0 += __shfl_xor(p0, off, 64);
        float ex0 = l0 ? __builtin_exp2f(p0) : 0.f;
        ssum += ex0;
        ax0 += ex0 * __uint_as_float(r0.x & 0xffff0000u);
        ax1 += ex0 * __uint_as_float(r0.y & 0xffff0000u);
        ax2 += ex0 * __uint_as_float(r0.z & 0xffff0000u);
        ax3 += ex0 * __uint_as_float(r0.w & 0xffff0000u);
    }
    ssum += __shfl_xor(ssum, 16, 64); ssum += __shfl_xor(ssum, 32, 64);
    ax0  += __shfl_xor(ax0, 16, 64);  ax0  += __shfl_xor(ax0, 32, 64);
    ax1  += __shfl_xor(ax1, 16, 64);  ax1  += __shfl_xor(ax1, 32, 64);
    ax2  += __shfl_xor(ax2, 16, 64);  ax2  += __shfl_xor(ax2, 32, 64);
    ax3  += __shfl_xor(ax3, 16, 64);  ax3  += __shfl_xor(ax3, 32, 64);
    if (h == 0) {
        float inv = (re > rs) ? 1.f / ssum : 0.f;
        float4 o = make_float4(ax0 * inv, ax1 * inv, ax2 * inv, ax3 * inv);
        *(float4*)&out[(size_t)node * D + 4 * q] = o;
    }
}

extern "C" void kernel_launch(void* const* d_in, const int* in_sizes, int n_in,
                              void* d_out, int out_size, void* d_ws, size_t ws_size,
                              hipStream_t stream) {
    const float* x   = (const float*)d_in[0];
    const int*   ei  = (const int*)d_in[1];
    const float* W   = (const float*)d_in[2];
    const float* b   = (const float*)d_in[3];
    const float* att = (const float*)d_in[4];
    int n = in_sizes[0] / D;
    int e = in_sizes[1] / 2;
    const int* src = ei;
    const int* dst = ei + e;
    float* out = (float*)d_out;

    int gemmBlk = (n + 63) / 64;                             // 1563
    int nb      = (n + BSZ - 1) >> BSH;                      // 782 buckets of 128
    int histBlk = (e + 256 * HEPT_H - 1) / (256 * HEPT_H);   // 147
    int nblk    = histBlk;
    int scatBlk = (e + 256 * SEPT - 1) / (256 * SEPT);       // 147
    int NBH     = nb * nblk;                                 // 114954 cells
    int scanBlk = (NBH + 255) / 256;                         // 450 (<= 1024)

    // ws: zxb[n*64 uint] | hist2d[NBH+1] | rowstart[n+1] | srcids[e] | packed[e] | part[1024]
    unsigned int* zxb = (unsigned int*)d_ws;
    int* hist2d   = (int*)(zxb + (size_t)n * 64);
    int* rowstart = hist2d + NBH + 1;
    int* srcids   = rowstart + n + 1;
    unsigned int* packed = (unsigned int*)(srcids + e);
    int* part     = (int*)(packed + e);

    gemm_z_hist<<<histBlk + gemmBlk, 256, 0, stream>>>(x, W, b, zxb, n,
                                                       dst, hist2d, e, histBlk, nb, nblk);
    scan_part<<<scanBlk, 256, 0, stream>>>(hist2d, part, NBH);
    scan_top<<<1, 1024, 0, stream>>>(part, scanBlk);
    scan_final_ip<<<scanBlk, 256, 0, stream>>>(hist2d, part, NBH);
    msd_scatter<<<scatBlk, 256, 0, stream>>>(src, dst, hist2d, packed, e, nb, nblk);
    bucket_csr<<<nb, 256, 0, stream>>>(packed, hist2d, rowstart, srcids, n, e, nb, nblk);
    gather4b<<<(n + 3) / 4, 256, 0, stream>>>(srcids, rowstart, zxb, att, out, n);
}

// Round 12
// 195.924 us; speedup vs baseline: 2.8646x; 1.0120x over previous
//
#include <hip/hip_runtime.h>

#define D 64
#define LOG2E 1.4426950408889634f

#define HEPT_H 32                 // edges/thread, fused hist blocks (8192/block)
#define SEPT 32                   // edges/thread, scatter (8192/block)
#define BSH 6                     // bucket shift: 64-node buckets
#define BSZ 64                    // nodes per bucket
#define CAP 1536                  // LDS edge capacity per gather block (~27 sigma)

using frag_ab = __attribute__((ext_vector_type(8))) short;  // 8 bf16 (4 VGPRs)
using f32x4   = __attribute__((ext_vector_type(4))) float;  // 4 fp32 acc

__device__ __forceinline__ unsigned short f2bf(float f) {      // RNE fp32->bf16
    unsigned int bits = __float_as_uint(f);
    return (unsigned short)((bits + 0x7fffu + ((bits >> 16) & 1u)) >> 16);
}

__device__ __forceinline__ frag_ab pack8(float4 a, float4 b) { // 8 fp32 -> bf16x8 frag
    frag_ab f;
    f[0] = (short)f2bf(a.x); f[1] = (short)f2bf(a.y);
    f[2] = (short)f2bf(a.z); f[3] = (short)f2bf(a.w);
    f[4] = (short)f2bf(b.x); f[5] = (short)f2bf(b.y);
    f[6] = (short)f2bf(b.z); f[7] = (short)f2bf(b.w);
    return f;
}

// Block-role fused kernel: blocks [0, histBlk) histogram dst>>BSH into a bin-major
// 2D count matrix hist2d[bin*nblk + blk] (plain stores, no global atomics);
// blocks [histBlk, ..) do z = x @ W^T + b via MFMA bf16, LDS-free (R7).
// zxb[row*64+c] = { bf16(z_c) | bf16(x_c)<<16 }.
__global__ __launch_bounds__(256) void gemm_z_hist(const float* __restrict__ x,
                                                   const float* __restrict__ W,
                                                   const float* __restrict__ b,
                                                   unsigned int* __restrict__ zxb,
                                                   int n,
                                                   const int* __restrict__ dst,
                                                   int* __restrict__ hist2d,
                                                   int e_cnt, int histBlk,
                                                   int nb, int nblk) {
    __shared__ int cnt[2048];       // hist branch only (8 KB; nb <= 2048)
    int tid = threadIdx.x;

    if ((int)blockIdx.x < histBlk) {
        for (int i = tid; i < nb; i += 256) cnt[i] = 0;
        __syncthreads();
        int base = blockIdx.x * (256 * HEPT_H);
        for (int j = 0; j < HEPT_H; ++j) {
            int e = base + j * 256 + tid;
            if (e < e_cnt) atomicAdd(&cnt[dst[e] >> BSH], 1);   // LDS atomic
        }
        __syncthreads();
        for (int i = tid; i < nb; i += 256)
            hist2d[(size_t)i * nblk + blockIdx.x] = cnt[i];     // bin-major store
        return;
    }

    int row0 = (blockIdx.x - histBlk) * 64;
    int l  = tid & 63;    // lane
    int w  = tid >> 6;    // wave 0..3 -> rows w*16..w*16+15
    int lr = l & 15;      // A-row / B-col / D-col within 16-tile
    int hi = l >> 4;      // 0..3
    int lk = hi * 8;      // k offset within K=32 chunk

    // A frags straight from global: wave reads 16 contiguous 256B rows (4 KB)
    int arow = row0 + w * 16 + lr;
    int crow = (arow < n) ? arow : (n - 1);       // clamp; stores are guarded
    const float* xp = x + (size_t)crow * 64;
    frag_ab afr[2];
#pragma unroll
    for (int ks = 0; ks < 2; ++ks) {
        const float* ap = xp + ks * 32 + lk;
        afr[ks] = pack8(*(const float4*)ap, *(const float4*)(ap + 4));
    }

    // B frags straight from W (16 KB, L1/L2-resident; B^T == W so k contiguous)
    frag_ab bfr[4][2];
#pragma unroll
    for (int colt = 0; colt < 4; ++colt) {
#pragma unroll
        for (int ks = 0; ks < 2; ++ks) {
            const float* wp = W + (colt * 16 + lr) * 64 + ks * 32 + lk;
            bfr[colt][ks] = pack8(*(const float4*)wp, *(const float4*)(wp + 4));
        }
    }

    f32x4 zero = {0.f, 0.f, 0.f, 0.f};
    f32x4 acc[4] = {zero, zero, zero, zero};
#pragma unroll
    for (int ks = 0; ks < 2; ++ks) {
#pragma unroll
        for (int colt = 0; colt < 4; ++colt) {
            acc[colt] = __builtin_amdgcn_mfma_f32_16x16x32_bf16(
                afr[ks], bfr[colt][ks], acc[colt], 0, 0, 0);
        }
    }

    // D mapping: col=lane&15, row=(lane>>4)*4+reg (m89-verified).
    // xv re-read from global is L1-hot (this block just streamed these rows).
#pragma unroll
    for (int colt = 0; colt < 4; ++colt) {
        int col = colt * 16 + lr;
        float bb = b[col];
#pragma unroll
        for (int r = 0; r < 4; ++r) {
            int row = row0 + w * 16 + hi * 4 + r;
            int rrow = (row < n) ? row : (n - 1);
            float z  = acc[colt][r] + bb;
            float xv = x[(size_t)rrow * 64 + col];
            unsigned int u = (unsigned int)f2bf(z) |
                             ((unsigned int)f2bf(xv) << 16);
            if (row < n)
                zxb[(size_t)row * 64 + col] = u;   // 64B-segment coalesced
        }
    }
}

// ---- scan pass 1: per-256-chunk sums ----
__global__ __launch_bounds__(256) void scan_part(const int* __restrict__ data,
                                                 int* __restrict__ part, int n) {
    __shared__ int red[256];
    int t = threadIdx.x;
    int i = blockIdx.x * 256 + t;
    red[t] = (i < n) ? data[i] : 0;
    __syncthreads();
    for (int off = 128; off >= 1; off >>= 1) {
        if (t < off) red[t] += red[t + off];
        __syncthreads();
    }
    if (t == 0) part[blockIdx.x] = red[0];
}

// ---- scan pass 2 (merged top+final): block b REDUCES part[0..b-1] (L2-hot,
// <=900 ints) instead of waiting on a separate single-block top-scan dispatch,
// then does the in-place per-cell exclusive scan. Sentinel: data[n] = total.
__global__ __launch_bounds__(256) void scan_final2(int* data,
                                                   const int* __restrict__ part,
                                                   int n) {
    __shared__ int red[256];
    __shared__ int s[256];
    int t = threadIdx.x;
    int b = blockIdx.x;
    int acc = 0;
    for (int i = t; i < b; i += 256) acc += part[i];
    red[t] = acc;
    __syncthreads();
    for (int off = 128; off >= 1; off >>= 1) {
        if (t < off) red[t] += red[t + off];
        __syncthreads();
    }
    int base = red[0];          // exclusive prefix of chunks before block b
    __syncthreads();

    int i = b * 256 + t;
    int v = (i < n) ? data[i] : 0;
    s[t] = v;
    __syncthreads();
    for (int off = 1; off < 256; off <<= 1) {
        int u = (t >= off) ? s[t - off] : 0;
        __syncthreads();
        s[t] += u;
        __syncthreads();
    }
    int incl = s[t] + base;
    if (i < n) data[i] = incl - v;
    if (i == n - 1) data[n] = incl;
}

// Partition edges into 64-node buckets: packed[pos] = src | (dst&63)<<24.
// Per-block bases come straight from the scanned 2D histogram -> disjoint output
// ranges with ZERO global atomics. 147 blocks, ~10-int runs per (bin,blk).
__global__ __launch_bounds__(256) void msd_scatter(const int* __restrict__ src,
                                                   const int* __restrict__ dst,
                                                   const int* __restrict__ histS,
                                                   unsigned int* __restrict__ packed,
                                                   int e_cnt, int nb, int nblk) {
    __shared__ int cnt[2048];
    int t = threadIdx.x;
    int blk = blockIdx.x;
    for (int i = t; i < nb; i += 256) cnt[i] = histS[(size_t)i * nblk + blk];
    __syncthreads();
    int base = blk * (256 * SEPT);
    for (int j = 0; j < SEPT; ++j) {
        int e = base + j * 256 + t;
        if (e < e_cnt) {
            int d = dst[e];
            int pos = atomicAdd(&cnt[d >> BSH], 1);          // LDS atomic only
            packed[pos] = (unsigned int)src[e] | ((unsigned int)(d & (BSZ - 1)) << 24);
        }
    }
}

// One block per 64-node bucket (~768 edges, 1563 blocks, 4 waves x 16 nodes).
// Builds the per-node CSR IN LDS (count -> scan -> scatter) from the bucket's
// contiguous packed[] slice, then gathers (R4-measured: 68 us, replaces
// bucket_csr + gather4b + the srcids HBM round-trip). Overflow -> srcfb.
__global__ __launch_bounds__(256) void gather_csr(const unsigned int* __restrict__ packed,
                                                  const int* __restrict__ histS,
                                                  int* __restrict__ srcfb,
                                                  const unsigned int* __restrict__ zxb,
                                                  const float* __restrict__ att,
                                                  float* __restrict__ out,
                                                  int n, int nblk) {
    __shared__ int srcs[CAP];
    __shared__ int cnt[BSZ];
    __shared__ int cur[BSZ];
    __shared__ int rowst[BSZ + 1];
    int t = threadIdx.x;
    int bkt = blockIdx.x;
    int lo = histS[(size_t)bkt * nblk];
    int m  = histS[(size_t)(bkt + 1) * nblk] - lo;   // last bkt hits sentinel
    bool ovf = (m > CAP);

    if (t < BSZ) cnt[t] = 0;
    __syncthreads();
    for (int i = t; i < m; i += 256)
        atomicAdd(&cnt[packed[lo + i] >> 24], 1);
    __syncthreads();
    if (t < BSZ) cur[t] = cnt[t];
    __syncthreads();
    for (int off = 1; off < BSZ; off <<= 1) {
        int u = (t < BSZ && t >= off) ? cur[t - off] : 0;
        __syncthreads();
        if (t < BSZ) cur[t] += u;
        __syncthreads();
    }
    if (t < BSZ) {
        rowst[t] = cur[t] - cnt[t];       // exclusive (bucket-local)
        cur[t]   = cur[t] - cnt[t];
    }
    if (t == 0) rowst[BSZ] = m;
    __syncthreads();
    for (int i = t; i < m; i += 256) {
        unsigned int p = packed[lo + i];
        int pos = atomicAdd(&cur[p >> 24], 1);               // LDS atomic
        int sv = (int)(p & 0xFFFFFFu);
        if (!ovf) srcs[pos] = sv;
        else      srcfb[lo + pos] = sv;                      // rare fallback
    }
    __syncthreads();

    // ---- gather: wave w handles nodes w*16 .. w*16+15 of this bucket ----
    int lane = t & 63;
    int w    = t >> 6;
    int q = lane & 15;                 // dim group: 4q..4q+3
    int h = lane >> 4;                 // edge slot 0..3
    float4 av = *(const float4*)(att + 4 * q);
    float a0 = av.x * LOG2E, a1 = av.y * LOG2E, a2 = av.z * LOG2E, a3 = av.w * LOG2E;
    const int* sg = srcfb + lo;

    for (int k = 0; k < 16; ++k) {
        int nl = w * 16 + k;
        int node = (bkt << BSH) + nl;
        if (node >= n) break;
        int rs = rowst[nl], re = rowst[nl + 1];

        const uint4 zdv = *(const uint4*)(zxb + (size_t)node * 64 + 4 * q);
        float zd0 = __uint_as_float(zdv.x << 16);
        float zd1 = __uint_as_float(zdv.y << 16);
        float zd2 = __uint_as_float(zdv.z << 16);
        float zd3 = __uint_as_float(zdv.w << 16);

        float ax0 = 0.f, ax1 = 0.f, ax2 = 0.f, ax3 = 0.f, ssum = 0.f;
        int efull = rs + ((re - rs) & ~7);
        int e = rs;
        for (; e < efull; e += 8) {            // unmasked body
            int i0 = e + h, i1 = e + 4 + h;
            int s0 = ovf ? sg[i0] : srcs[i0];
            int s1 = ovf ? sg[i1] : srcs[i1];
            const uint4 r0 = *(const uint4*)(zxb + (size_t)s0 * 64 + 4 * q);
            const uint4 r1 = *(const uint4*)(zxb + (size_t)s1 * 64 + 4 * q);

            float v0 = __uint_as_float(r0.x << 16) + zd0; v0 = fmaxf(v0, 0.2f * v0);
            float v1 = __uint_as_float(r0.y << 16) + zd1; v1 = fmaxf(v1, 0.2f * v1);
            float v2 = __uint_as_float(r0.z << 16) + zd2; v2 = fmaxf(v2, 0.2f * v2);
            float v3 = __uint_as_float(r0.w << 16) + zd3; v3 = fmaxf(v3, 0.2f * v3);
            float p0 = v0 * a0 + v1 * a1 + v2 * a2 + v3 * a3;

            float u0 = __uint_as_float(r1.x << 16) + zd0; u0 = fmaxf(u0, 0.2f * u0);
            float u1 = __uint_as_float(r1.y << 16) + zd1; u1 = fmaxf(u1, 0.2f * u1);
            float u2 = __uint_as_float(r1.z << 16) + zd2; u2 = fmaxf(u2, 0.2f * u2);
            float u3 = __uint_as_float(r1.w << 16) + zd3; u3 = fmaxf(u3, 0.2f * u3);
            float p1 = u0 * a0 + u1 * a1 + u2 * a2 + u3 * a3;

#pragma unroll
            for (int off = 8; off >= 1; off >>= 1) {
                p0 += __shfl_xor(p0, off, 64);
                p1 += __shfl_xor(p1, off, 64);
            }
            float ex0 = __builtin_exp2f(p0);
            float ex1 = __builtin_exp2f(p1);
            ssum += ex0 + ex1;
            ax0 += ex0 * __uint_as_float(r0.x & 0xffff0000u)
                 + ex1 * __uint_as_float(r1.x & 0xffff0000u);
            ax1 += ex0 * __uint_as_float(r0.y & 0xffff0000u)
                 + ex1 * __uint_as_float(r1.y & 0xffff0000u);
            ax2 += ex0 * __uint_as_float(r0.z & 0xffff0000u)
                 + ex1 * __uint_as_float(r1.z & 0xffff0000u);
            ax3 += ex0 * __uint_as_float(r0.w & 0xffff0000u)
                 + ex1 * __uint_as_float(r1.w & 0xffff0000u);
        }
        if (e < re) {                          // masked tail (1..7 edges)
            int i0 = e + h, i1 = e + 4 + h;
            bool l0 = i0 < re, l1 = i1 < re;
            int s0 = l0 ? (ovf ? sg[i0] : srcs[i0]) : node;
            int s1 = l1 ? (ovf ? sg[i1] : srcs[i1]) : node;
            const uint4 r0 = *(const uint4*)(zxb + (size_t)s0 * 64 + 4 * q);
            const uint4 r1 = *(const uint4*)(zxb + (size_t)s1 * 64 + 4 * q);

            float v0 = __uint_as_float(r0.x << 16) + zd0; v0 = fmaxf(v0, 0.2f * v0);
            float v1 = __uint_as_float(r0.y << 16) + zd1; v1 = fmaxf(v1, 0.2f * v1);
            float v2 = __uint_as_float(r0.z << 16) + zd2; v2 = fmaxf(v2, 0.2f * v2);
            float v3 = __uint_as_float(r0.w << 16) + zd3; v3 = fmaxf(v3, 0.2f * v3);
            float p0 = v0 * a0 + v1 * a1 + v2 * a2 + v3 * a3;

            float u0 = __uint_as_float(r1.x << 16) + zd0; u0 = fmaxf(u0, 0.2f * u0);
            float u1 = __uint_as_float(r1.y << 16) + zd1; u1 = fmaxf(u1, 0.2f * u1);
            float u2 = __uint_as_float(r1.z << 16) + zd2; u2 = fmaxf(u2, 0.2f * u2);
            float u3 = __uint_as_float(r1.w << 16) + zd3; u3 = fmaxf(u3, 0.2f * u3);
            float p1 = u0 * a0 + u1 * a1 + u2 * a2 + u3 * a3;

#pragma unroll
            for (int off = 8; off >= 1; off >>= 1) {
                p0 += __shfl_xor(p0, off, 64);
                p1 += __shfl_xor(p1, off, 64);
            }
            float ex0 = l0 ? __builtin_exp2f(p0) : 0.f;
            float ex1 = l1 ? __builtin_exp2f(p1) : 0.f;
            ssum += ex0 + ex1;
            ax0 += ex0 * __uint_as_float(r0.x & 0xffff0000u)
                 + ex1 * __uint_as_float(r1.x & 0xffff0000u);
            ax1 += ex0 * __uint_as_float(r0.y & 0xffff0000u)
                 + ex1 * __uint_as_float(r1.y & 0xffff0000u);
            ax2 += ex0 * __uint_as_float(r0.z & 0xffff0000u)
                 + ex1 * __uint_as_float(r1.z & 0xffff0000u);
            ax3 += ex0 * __uint_as_float(r0.w & 0xffff0000u)
                 + ex1 * __uint_as_float(r1.w & 0xffff0000u);
        }
        ssum += __shfl_xor(ssum, 16, 64); ssum += __shfl_xor(ssum, 32, 64);
        ax0  += __shfl_xor(ax0, 16, 64);  ax0  += __shfl_xor(ax0, 32, 64);
        ax1  += __shfl_xor(ax1, 16, 64);  ax1  += __shfl_xor(ax1, 32, 64);
        ax2  += __shfl_xor(ax2, 16, 64);  ax2  += __shfl_xor(ax2, 32, 64);
        ax3  += __shfl_xor(ax3, 16, 64);  ax3  += __shfl_xor(ax3, 32, 64);
        if (h == 0) {
            float inv = (re > rs) ? 1.f / ssum : 0.f;
            float4 o = make_float4(ax0 * inv, ax1 * inv, ax2 * inv, ax3 * inv);
            *(float4*)&out[(size_t)node * D + 4 * q] = o;
        }
    }
}

extern "C" void kernel_launch(void* const* d_in, const int* in_sizes, int n_in,
                              void* d_out, int out_size, void* d_ws, size_t ws_size,
                              hipStream_t stream) {
    const float* x   = (const float*)d_in[0];
    const int*   ei  = (const int*)d_in[1];
    const float* W   = (const float*)d_in[2];
    const float* b   = (const float*)d_in[3];
    const float* att = (const float*)d_in[4];
    int n = in_sizes[0] / D;
    int e = in_sizes[1] / 2;
    const int* src = ei;
    const int* dst = ei + e;
    float* out = (float*)d_out;

    int gemmBlk = (n + 63) / 64;                             // 1563
    int nb      = (n + BSZ - 1) >> BSH;                      // 1563 buckets of 64
    int histBlk = (e + 256 * HEPT_H - 1) / (256 * HEPT_H);   // 147
    int nblk    = histBlk;
    int scatBlk = (e + 256 * SEPT - 1) / (256 * SEPT);       // 147
    int NBH     = nb * nblk;                                 // 229,761 cells
    int scanBlk = (NBH + 255) / 256;                         // 898

    // ws: zxb[n*64 uint] | hist2d[NBH+1] | packed[e] | srcfb[e] | part[1024]
    unsigned int* zxb = (unsigned int*)d_ws;
    int* hist2d   = (int*)(zxb + (size_t)n * 64);
    unsigned int* packed = (unsigned int*)(hist2d + NBH + 1);
    int* srcfb    = (int*)(packed + e);
    int* part     = srcfb + e;

    gemm_z_hist<<<histBlk + gemmBlk, 256, 0, stream>>>(x, W, b, zxb, n,
                                                       dst, hist2d, e, histBlk, nb, nblk);
    scan_part<<<scanBlk, 256, 0, stream>>>(hist2d, part, NBH);
    scan_final2<<<scanBlk, 256, 0, stream>>>(hist2d, part, NBH);
    msd_scatter<<<scatBlk, 256, 0, stream>>>(src, dst, hist2d, packed, e, nb, nblk);
    gather_csr<<<nb, 256, 0, stream>>>(packed, hist2d, srcfb, zxb, att, out, n, nblk);
}

// Round 14
// 186.912 us; speedup vs baseline: 3.0027x; 1.0482x over previous
//
#include <hip/hip_runtime.h>

#define D 64
#define LOG2E 1.4426950408889634f

#define HEPT_H 32                 // edges/thread, fused hist blocks (8192/block)
#define SEPT 8                    // edges/thread, scatter (1024 thr -> 8192/block)
#define BSH 7                     // bucket shift: 128-node buckets
#define BSZ 128                   // nodes per bucket

using frag_ab = __attribute__((ext_vector_type(8))) short;  // 8 bf16 (4 VGPRs)
using f32x4   = __attribute__((ext_vector_type(4))) float;  // 4 fp32 acc

__device__ __forceinline__ unsigned short f2bf(float f) {      // RNE fp32->bf16
    unsigned int bits = __float_as_uint(f);
    return (unsigned short)((bits + 0x7fffu + ((bits >> 16) & 1u)) >> 16);
}

__device__ __forceinline__ frag_ab pack8(float4 a, float4 b) { // 8 fp32 -> bf16x8 frag
    frag_ab f;
    f[0] = (short)f2bf(a.x); f[1] = (short)f2bf(a.y);
    f[2] = (short)f2bf(a.z); f[3] = (short)f2bf(a.w);
    f[4] = (short)f2bf(b.x); f[5] = (short)f2bf(b.y);
    f[6] = (short)f2bf(b.z); f[7] = (short)f2bf(b.w);
    return f;
}

// Block-role fused kernel: blocks [0, histBlk) histogram dst>>BSH into a bin-major
// 2D count matrix hist2d[bin*nblk + blk] (plain stores, no global atomics);
// blocks [histBlk, ..) do z = x @ W^T + b via MFMA bf16, LDS-free (R7).
// zxb[row*64+c] = { bf16(z_c) | bf16(x_c)<<16 }.
__global__ __launch_bounds__(256) void gemm_z_hist(const float* __restrict__ x,
                                                   const float* __restrict__ W,
                                                   const float* __restrict__ b,
                                                   unsigned int* __restrict__ zxb,
                                                   int n,
                                                   const int* __restrict__ dst,
                                                   int* __restrict__ hist2d,
                                                   int e_cnt, int histBlk,
                                                   int nb, int nblk) {
    __shared__ int cnt[2048];       // hist branch only (8 KB; nb <= 2048)
    int tid = threadIdx.x;

    if ((int)blockIdx.x < histBlk) {
        for (int i = tid; i < nb; i += 256) cnt[i] = 0;
        __syncthreads();
        int base = blockIdx.x * (256 * HEPT_H);
        for (int j = 0; j < HEPT_H; ++j) {
            int e = base + j * 256 + tid;
            if (e < e_cnt) atomicAdd(&cnt[dst[e] >> BSH], 1);   // LDS atomic
        }
        __syncthreads();
        for (int i = tid; i < nb; i += 256)
            hist2d[(size_t)i * nblk + blockIdx.x] = cnt[i];     // bin-major store
        return;
    }

    int row0 = (blockIdx.x - histBlk) * 64;
    int l  = tid & 63;    // lane
    int w  = tid >> 6;    // wave 0..3 -> rows w*16..w*16+15
    int lr = l & 15;      // A-row / B-col / D-col within 16-tile
    int hi = l >> 4;      // 0..3
    int lk = hi * 8;      // k offset within K=32 chunk

    // A frags straight from global: wave reads 16 contiguous 256B rows (4 KB)
    int arow = row0 + w * 16 + lr;
    int crow = (arow < n) ? arow : (n - 1);       // clamp; stores are guarded
    const float* xp = x + (size_t)crow * 64;
    frag_ab afr[2];
#pragma unroll
    for (int ks = 0; ks < 2; ++ks) {
        const float* ap = xp + ks * 32 + lk;
        afr[ks] = pack8(*(const float4*)ap, *(const float4*)(ap + 4));
    }

    // B frags straight from W (16 KB, L1/L2-resident; B^T == W so k contiguous)
    frag_ab bfr[4][2];
#pragma unroll
    for (int colt = 0; colt < 4; ++colt) {
#pragma unroll
        for (int ks = 0; ks < 2; ++ks) {
            const float* wp = W + (colt * 16 + lr) * 64 + ks * 32 + lk;
            bfr[colt][ks] = pack8(*(const float4*)wp, *(const float4*)(wp + 4));
        }
    }

    f32x4 zero = {0.f, 0.f, 0.f, 0.f};
    f32x4 acc[4] = {zero, zero, zero, zero};
#pragma unroll
    for (int ks = 0; ks < 2; ++ks) {
#pragma unroll
        for (int colt = 0; colt < 4; ++colt) {
            acc[colt] = __builtin_amdgcn_mfma_f32_16x16x32_bf16(
                afr[ks], bfr[colt][ks], acc[colt], 0, 0, 0);
        }
    }

    // D mapping: col=lane&15, row=(lane>>4)*4+reg (m89-verified).
    // xv re-read from global is L1-hot (this block just streamed these rows).
#pragma unroll
    for (int colt = 0; colt < 4; ++colt) {
        int col = colt * 16 + lr;
        float bb = b[col];
#pragma unroll
        for (int r = 0; r < 4; ++r) {
            int row = row0 + w * 16 + hi * 4 + r;
            int rrow = (row < n) ? row : (n - 1);
            float z  = acc[colt][r] + bb;
            float xv = x[(size_t)rrow * 64 + col];
            unsigned int u = (unsigned int)f2bf(z) |
                             ((unsigned int)f2bf(xv) << 16);
            if (row < n)
                zxb[(size_t)row * 64 + col] = u;   // 64B-segment coalesced
        }
    }
}

// ---- 3-phase coalesced scan over the bin-major histogram (atomic-free) ----
__global__ __launch_bounds__(256) void scan_part(const int* __restrict__ data,
                                                 int* __restrict__ part, int n) {
    __shared__ int red[256];
    int t = threadIdx.x;
    int i = blockIdx.x * 256 + t;
    red[t] = (i < n) ? data[i] : 0;
    __syncthreads();
    for (int off = 128; off >= 1; off >>= 1) {
        if (t < off) red[t] += red[t + off];
        __syncthreads();
    }
    if (t == 0) part[blockIdx.x] = red[0];
}

__global__ __launch_bounds__(1024) void scan_top(int* __restrict__ part, int B) {
    __shared__ int s[1024];
    int t = threadIdx.x;
    int v = (t < B) ? part[t] : 0;
    s[t] = v;
    __syncthreads();
    for (int off = 1; off < 1024; off <<= 1) {
        int u = (t >= off) ? s[t - off] : 0;
        __syncthreads();
        s[t] += u;
        __syncthreads();
    }
    if (t < B) part[t] = s[t] - v;   // exclusive
}

// in-place exclusive scan finalize (read-before-write, 1 thread per index).
// Writes total at data[n] as sentinel.
__global__ __launch_bounds__(256) void scan_final_ip(int* data,
                                                     const int* __restrict__ part, int n) {
    __shared__ int s[256];
    int t = threadIdx.x;
    int i = blockIdx.x * 256 + t;
    int v = (i < n) ? data[i] : 0;
    s[t] = v;
    __syncthreads();
    for (int off = 1; off < 256; off <<= 1) {
        int u = (t >= off) ? s[t - off] : 0;
        __syncthreads();
        s[t] += u;
        __syncthreads();
    }
    int incl = s[t] + part[blockIdx.x];
    if (i < n) data[i] = incl - v;
    if (i == n - 1) data[n] = incl;
}

// Partition edges into 128-node buckets: packed[pos] = src | (dst&127)<<24.
// Per-block bases come straight from the scanned 2D histogram -> disjoint output
// ranges with ZERO global atomics. SAME 8192-edge chunk (147 blocks, 10.5-int
// runs preserved — R8 lesson) but 1024 threads: 16 waves/CU instead of 4 and
// dependent-round depth 32 -> 8 for latency hiding.
__global__ __launch_bounds__(1024) void msd_scatter(const int* __restrict__ src,
                                                    const int* __restrict__ dst,
                                                    const int* __restrict__ histS,
                                                    unsigned int* __restrict__ packed,
                                                    int e_cnt, int nb, int nblk) {
    __shared__ int cnt[1024];
    int t = threadIdx.x;
    int blk = blockIdx.x;
    for (int i = t; i < nb; i += 1024) cnt[i] = histS[(size_t)i * nblk + blk];
    __syncthreads();
    int base = blk * (1024 * SEPT);
    for (int j = 0; j < SEPT; ++j) {
        int e = base + j * 1024 + t;
        if (e < e_cnt) {
            int d = dst[e];
            int pos = atomicAdd(&cnt[d >> BSH], 1);          // LDS atomic only
            packed[pos] = (unsigned int)src[e] | ((unsigned int)(d & (BSZ - 1)) << 24);
        }
    }
}

// One block per 128-node bucket (~1536 edges avg, 782 blocks). LDS count + scan ->
// rowstart written directly; srcids scattered within the bucket's contiguous region.
__global__ __launch_bounds__(256) void bucket_csr(const unsigned int* __restrict__ packed,
                                                  const int* __restrict__ histS,
                                                  int* __restrict__ rowstart,
                                                  int* __restrict__ srcids,
                                                  int n, int e_cnt, int nb, int nblk) {
    __shared__ int cnt[128];
    __shared__ int sc[128];
    __shared__ int cur[128];
    int t = threadIdx.x;
    int b = blockIdx.x;
    int lo = histS[(size_t)b * nblk];
    int hi = histS[(size_t)(b + 1) * nblk];   // b==nb-1 hits sentinel == e_cnt
    int m = hi - lo;

    if (t < 128) cnt[t] = 0;
    __syncthreads();
    for (int i = t; i < m; i += 256)
        atomicAdd(&cnt[packed[lo + i] >> 24], 1);
    __syncthreads();
    if (t < 128) sc[t] = cnt[t];
    __syncthreads();
    for (int off = 1; off < 128; off <<= 1) {
        int u = (t < 128 && t >= off) ? sc[t - off] : 0;
        __syncthreads();
        if (t < 128) sc[t] += u;
        __syncthreads();
    }
    if (t < 128) {
        int excl = sc[t] - cnt[t];
        cur[t] = lo + excl;
        int node = (b << BSH) + t;
        if (node < n) rowstart[node] = lo + excl;
    }
    if (b == nb - 1 && t == 0) rowstart[n] = e_cnt;
    __syncthreads();
    for (int i = t; i < m; i += 256) {
        unsigned int p = packed[lo + i];
        int pos = atomicAdd(&cur[p >> 24], 1);     // LDS atomic
        srcids[pos] = (int)(p & 0xFFFFFFu);
    }
}

// wave-per-node, quarter-wave per edge, 8 edges/iter (2x unroll); unmasked full
// iterations + one masked tail. lrelu = max(v, 0.2v) (2 ops, slope < 1).
// bf16-packed row: zxb[row*64 + d] = { bf16 z_d | bf16 x_d << 16 }, 256 B/row.
__global__ __launch_bounds__(256) void gather4b(const int* __restrict__ srcids,
                                                const int* __restrict__ rowstart,
                                                const unsigned int* __restrict__ zxb,
                                                const float* __restrict__ att,
                                                float* __restrict__ out, int n) {
    int lane = threadIdx.x & 63;
    int node = blockIdx.x * 4 + (threadIdx.x >> 6);
    if (node >= n) return;
    int q = lane & 15;                 // dim group: 4q..4q+3
    int h = lane >> 4;                 // edge slot 0..3
    int rs = rowstart[node], re = rowstart[node + 1];

    const uint4 zdv = *(const uint4*)(zxb + (size_t)node * 64 + 4 * q);
    float zd0 = __uint_as_float(zdv.x << 16);
    float zd1 = __uint_as_float(zdv.y << 16);
    float zd2 = __uint_as_float(zdv.z << 16);
    float zd3 = __uint_as_float(zdv.w << 16);
    float4 av = *(const float4*)(att + 4 * q);
    float a0 = av.x * LOG2E, a1 = av.y * LOG2E, a2 = av.z * LOG2E, a3 = av.w * LOG2E;

    float ax0 = 0.f, ax1 = 0.f, ax2 = 0.f, ax3 = 0.f, ssum = 0.f;
    int efull = rs + ((re - rs) & ~7);
    int e = rs;
    for (; e < efull; e += 8) {            // unmasked body
        int s0 = srcids[e + h];
        int s1 = srcids[e + 4 + h];
        const uint4 r0 = *(const uint4*)(zxb + (size_t)s0 * 64 + 4 * q);
        const uint4 r1 = *(const uint4*)(zxb + (size_t)s1 * 64 + 4 * q);

        float v0 = __uint_as_float(r0.x << 16) + zd0; v0 = fmaxf(v0, 0.2f * v0);
        float v1 = __uint_as_float(r0.y << 16) + zd1; v1 = fmaxf(v1, 0.2f * v1);
        float v2 = __uint_as_float(r0.z << 16) + zd2; v2 = fmaxf(v2, 0.2f * v2);
        float v3 = __uint_as_float(r0.w << 16) + zd3; v3 = fmaxf(v3, 0.2f * v3);
        float p0 = v0 * a0 + v1 * a1 + v2 * a2 + v3 * a3;

        float u0 = __uint_as_float(r1.x << 16) + zd0; u0 = fmaxf(u0, 0.2f * u0);
        float u1 = __uint_as_float(r1.y << 16) + zd1; u1 = fmaxf(u1, 0.2f * u1);
        float u2 = __uint_as_float(r1.z << 16) + zd2; u2 = fmaxf(u2, 0.2f * u2);
        float u3 = __uint_as_float(r1.w << 16) + zd3; u3 = fmaxf(u3, 0.2f * u3);
        float p1 = u0 * a0 + u1 * a1 + u2 * a2 + u3 * a3;

#pragma unroll
        for (int off = 8; off >= 1; off >>= 1) {
            p0 += __shfl_xor(p0, off, 64);
            p1 += __shfl_xor(p1, off, 64);
        }
        float ex0 = __builtin_exp2f(p0);
        float ex1 = __builtin_exp2f(p1);
        ssum += ex0 + ex1;
        ax0 += ex0 * __uint_as_float(r0.x & 0xffff0000u)
             + ex1 * __uint_as_float(r1.x & 0xffff0000u);
        ax1 += ex0 * __uint_as_float(r0.y & 0xffff0000u)
             + ex1 * __uint_as_float(r1.y & 0xffff0000u);
        ax2 += ex0 * __uint_as_float(r0.z & 0xffff0000u)
             + ex1 * __uint_as_float(r1.z & 0xffff0000u);
        ax3 += ex0 * __uint_as_float(r0.w & 0xffff0000u)
             + ex1 * __uint_as_float(r1.w & 0xffff0000u);
    }
    if (e < re) {                          // masked tail (1..7 edges)
        int e0i = e + h, e1i = e + 4 + h;
        bool l0 = e0i < re, l1 = e1i < re;
        int s0 = l0 ? srcids[e0i] : node;
        int s1 = l1 ? srcids[e1i] : node;
        const uint4 r0 = *(const uint4*)(zxb + (size_t)s0 * 64 + 4 * q);
        const uint4 r1 = *(const uint4*)(zxb + (size_t)s1 * 64 + 4 * q);

        float v0 = __uint_as_float(r0.x << 16) + zd0; v0 = fmaxf(v0, 0.2f * v0);
        float v1 = __uint_as_float(r0.y << 16) + zd1; v1 = fmaxf(v1, 0.2f * v1);
        float v2 = __uint_as_float(r0.z << 16) + zd2; v2 = fmaxf(v2, 0.2f * v2);
        float v3 = __uint_as_float(r0.w << 16) + zd3; v3 = fmaxf(v3, 0.2f * v3);
        float p0 = v0 * a0 + v1 * a1 + v2 * a2 + v3 * a3;

        float u0 = __uint_as_float(r1.x << 16) + zd0; u0 = fmaxf(u0, 0.2f * u0);
        float u1 = __uint_as_float(r1.y << 16) + zd1; u1 = fmaxf(u1, 0.2f * u1);
        float u2 = __uint_as_float(r1.z << 16) + zd2; u2 = fmaxf(u2, 0.2f * u2);
        float u3 = __uint_as_float(r1.w << 16) + zd3; u3 = fmaxf(u3, 0.2f * u3);
        float p1 = u0 * a0 + u1 * a1 + u2 * a2 + u3 * a3;

#pragma unroll
        for (int off = 8; off >= 1; off >>= 1) {
            p0 += __shfl_xor(p0, off, 64);
            p1 += __shfl_xor(p1, off, 64);
        }
        float ex0 = l0 ? __builtin_exp2f(p0) : 0.f;
        float ex1 = l1 ? __builtin_exp2f(p1) : 0.f;
        ssum += ex0 + ex1;
        ax0 += ex0 * __uint_as_float(r0.x & 0xffff0000u)
             + ex1 * __uint_as_float(r1.x & 0xffff0000u);
        ax1 += ex0 * __uint_as_float(r0.y & 0xffff0000u)
             + ex1 * __uint_as_float(r1.y & 0xffff0000u);
        ax2 += ex0 * __uint_as_float(r0.z & 0xffff0000u)
             + ex1 * __uint_as_float(r1.z & 0xffff0000u);
        ax3 += ex0 * __uint_as_float(r0.w & 0xffff0000u)
             + ex1 * __uint_as_float(r1.w & 0xffff0000u);
    }
    ssum += __shfl_xor(ssum, 16, 64); ssum += __shfl_xor(ssum, 32, 64);
    ax0  += __shfl_xor(ax0, 16, 64);  ax0  += __shfl_xor(ax0, 32, 64);
    ax1  += __shfl_xor(ax1, 16, 64);  ax1  += __shfl_xor(ax1, 32, 64);
    ax2  += __shfl_xor(ax2, 16, 64);  ax2  += __shfl_xor(ax2, 32, 64);
    ax3  += __shfl_xor(ax3, 16, 64);  ax3  += __shfl_xor(ax3, 32, 64);
    if (h == 0) {
        float inv = (re > rs) ? 1.f / ssum : 0.f;
        float4 o = make_float4(ax0 * inv, ax1 * inv, ax2 * inv, ax3 * inv);
        *(float4*)&out[(size_t)node * D + 4 * q] = o;
    }
}

extern "C" void kernel_launch(void* const* d_in, const int* in_sizes, int n_in,
                              void* d_out, int out_size, void* d_ws, size_t ws_size,
                              hipStream_t stream) {
    const float* x   = (const float*)d_in[0];
    const int*   ei  = (const int*)d_in[1];
    const float* W   = (const float*)d_in[2];
    const float* b   = (const float*)d_in[3];
    const float* att = (const float*)d_in[4];
    int n = in_sizes[0] / D;
    int e = in_sizes[1] / 2;
    const int* src = ei;
    const int* dst = ei + e;
    float* out = (float*)d_out;

    int gemmBlk = (n + 63) / 64;                             // 1563
    int nb      = (n + BSZ - 1) >> BSH;                      // 782 buckets of 128
    int histBlk = (e + 256 * HEPT_H - 1) / (256 * HEPT_H);   // 147
    int nblk    = histBlk;
    int scatBlk = (e + 1024 * SEPT - 1) / (1024 * SEPT);     // 147 (same chunks)
    int NBH     = nb * nblk;                                 // 114954 cells
    int scanBlk = (NBH + 255) / 256;                         // 450 (<= 1024)

    // ws: zxb[n*64 uint] | hist2d[NBH+1] | rowstart[n+1] | srcids[e] | packed[e] | part[1024]
    unsigned int* zxb = (unsigned int*)d_ws;
    int* hist2d   = (int*)(zxb + (size_t)n * 64);
    int* rowstart = hist2d + NBH + 1;
    int* srcids   = rowstart + n + 1;
    unsigned int* packed = (unsigned int*)(srcids + e);
    int* part     = (int*)(packed + e);

    gemm_z_hist<<<histBlk + gemmBlk, 256, 0, stream>>>(x, W, b, zxb, n,
                                                       dst, hist2d, e, histBlk, nb, nblk);
    scan_part<<<scanBlk, 256, 0, stream>>>(hist2d, part, NBH);
    scan_top<<<1, 1024, 0, stream>>>(part, scanBlk);
    scan_final_ip<<<scanBlk, 256, 0, stream>>>(hist2d, part, NBH);
    msd_scatter<<<scatBlk, 1024, 0, stream>>>(src, dst, hist2d, packed, e, nb, nblk);
    bucket_csr<<<nb, 256, 0, stream>>>(packed, hist2d, rowstart, srcids, n, e, nb, nblk);
    gather4b<<<(n + 3) / 4, 256, 0, stream>>>(srcids, rowstart, zxb, att, out, n);
}